// Round 4
// baseline (431.408 us; speedup 1.0000x reference)
//
#include <hip/hip_runtime.h>
#include <hip/hip_fp16.h>

// SelfAttention: B=8, C=64, N=4096, d_head=8.
// o[b,c,m] = gamma * sum_n h[b,c,n] * softmax_n(f[:,n].g[:,m]) + x[b,c,m]
// R17: attn forced under the 64-VGPR occupancy cliff (m69: waves/SIMD halves
// at 64) via __launch_bounds__(256,8): l-sum back to VALU adds (+final shfl,
// frees ones8+accL = 12 regs), QK pairs interleaved with PAIR consumers
// (16 st regs live, not 32), 2-buffer LDS (16 KB -> 8 blocks/CU fits),
// S=8 so the grid supplies 8 blocks/CU. DMA staging + counted vmcnt kept.

typedef _Float16 half8_t __attribute__((ext_vector_type(8)));
typedef _Float16 half4_t __attribute__((ext_vector_type(4)));
typedef _Float16 half2_t __attribute__((ext_vector_type(2)));
typedef __fp16  fp16x2  __attribute__((ext_vector_type(2)));
typedef float float4_t __attribute__((ext_vector_type(4)));

#define NTOK 4096
#define PRH 72   // proj LDS row stride in halves
#define LOG2E 1.44269504088896340736f

#if __has_builtin(__builtin_amdgcn_exp2f)
__device__ __forceinline__ float fexp2(float x) { return __builtin_amdgcn_exp2f(x); }
#else
__device__ __forceinline__ float fexp2(float x) { return exp2f(x); }
#endif

__device__ __forceinline__ half2_t pkcvt(float a, float b) {
    fp16x2 v = __builtin_amdgcn_cvt_pkrtz(a, b);
    return __builtin_bit_cast(half2_t, v);
}

__device__ __forceinline__ float4_t mfma16(half4_t a, half4_t b, float4_t c) {
    return __builtin_amdgcn_mfma_f32_16x16x16f16(a, b, c, 0, 0, 0);
}
__device__ __forceinline__ float4_t mfma32(half8_t a, half8_t b, float4_t c) {
    return __builtin_amdgcn_mfma_f32_16x16x32_f16(a, b, c, 0, 0, 0);
}

#define GLDS(G, L) __builtin_amdgcn_global_load_lds(                            \
    (const __attribute__((address_space(1))) unsigned int*)(G),                 \
    (__attribute__((address_space(3))) unsigned int*)(L), 16, 0, 0)

// counted wait + raw barrier: tile DMA (issued first this iter) retired,
// f-record loads (issued after) may stay in flight
#define WAITVM2_BAR() do {                                                      \
    __builtin_amdgcn_sched_barrier(0);                                          \
    asm volatile("s_waitcnt vmcnt(2)" ::: "memory");                            \
    __builtin_amdgcn_sched_barrier(0);                                          \
    __builtin_amdgcn_s_barrier();                                               \
} while (0)

// ---------------- projection (MFMA) ------------------------------------------
// grid (128 token-tiles of 32, 8 b), block 320 = 5 waves = 5 out-row-groups.
// wave0 rows = Wq(8)+Wk(8); waves1-4 = Wv rows. x staged transposed to LDS
// fp16 with XOR channel swizzle. fTR records: [b][kt64*16+ml][q][t4][4] halves;
// q>=2 slots are the K-pad constants. hM stored PAIRED:
// hM[b][ch][kt64][pos] with pos = (t4>>1)*32 + (ml>>2)*8 + (t4&1)*4 + (ml&3)
// (key = kt64*64 + t4*16 + ml), so attn PV A-frags are contiguous b128.
__global__ __launch_bounds__(320) void proj_kernel(
    const float* __restrict__ x,
    const float* __restrict__ Wq, const float* __restrict__ bq,
    const float* __restrict__ Wk, const float* __restrict__ bk,
    const float* __restrict__ Wv, const float* __restrict__ bv,
    __half* __restrict__ fTR, __half* __restrict__ gT16, __half* __restrict__ hM)
{
    __shared__ __align__(16) _Float16 xh[32 * PRH];   // 4.6 KB
    const int t      = threadIdx.x;
    const int blk    = blockIdx.x;
    const int b      = blockIdx.y;
    const int n0     = blk * 32;
    const int kt64   = blk >> 1;
    const int t4base = (blk & 1) * 2;

    // stage x[b][c][n0..+31] -> xh[tok][c ^ swz] fp16
    if (t < 256) {
#pragma unroll
        for (int i = 0; i < 2; i++) {
            const int idx = t + i * 256;
            const int c = idx >> 3, f4 = idx & 7;          // tokens f4*4..+3
            float4 v = *(const float4*)(x + (((size_t)(b * 64 + c)) << 12) + n0 + f4 * 4);
            const int cs = c ^ ((f4 & 3) << 4);
            xh[(f4 * 4 + 0) * PRH + cs] = (_Float16)v.x;
            xh[(f4 * 4 + 1) * PRH + cs] = (_Float16)v.y;
            xh[(f4 * 4 + 2) * PRH + cs] = (_Float16)v.z;
            xh[(f4 * 4 + 3) * PRH + cs] = (_Float16)v.w;
        }
    }

    const int w    = t >> 6;
    const int lane = t & 63;
    const int q    = lane >> 4;
    const int ml   = lane & 15;

    // A-frags: W row, k = ks*16 + q*4 + j
    const float* wrow;
    if (w == 0) wrow = (ml < 8) ? (Wq + ml * 64) : (Wk + (ml - 8) * 64);
    else        wrow = Wv + ((w - 1) * 16 + ml) * 64;
    half4_t afr[4];
#pragma unroll
    for (int ks = 0; ks < 4; ks++) {
        float4 wv4 = *(const float4*)(wrow + ks * 16 + q * 4);
        afr[ks] = (half4_t){(_Float16)wv4.x, (_Float16)wv4.y,
                            (_Float16)wv4.z, (_Float16)wv4.w};
    }
    float4 bias4;
    if (w == 0) bias4 = (q < 2) ? *(const float4*)(bq + q * 4)
                                : *(const float4*)(bk + (q - 2) * 4);
    else        bias4 = *(const float4*)(bv + (w - 1) * 16 + q * 4);

    __syncthreads();

#pragma unroll
    for (int cg = 0; cg < 2; cg++) {
        const int tok  = cg * 16 + ml;                  // local token
        const int swz  = (tok >> 2) & 3;
        float4_t acc = (float4_t){0.f, 0.f, 0.f, 0.f};
#pragma unroll
        for (int ks = 0; ks < 4; ks++) {
            half4_t bfr = *(const half4_t*)(&xh[tok * PRH + ((ks ^ swz) * 16 + q * 4)]);
            acc = __builtin_amdgcn_mfma_f32_16x16x16f16(afr[ks], bfr, acc, 0, 0, 0);
        }
        acc[0] += bias4.x; acc[1] += bias4.y; acc[2] += bias4.z; acc[3] += bias4.w;
        const int gtok = n0 + tok;
        const int t4   = t4base + cg;

        if (w == 0) {
            __half* rec = fTR + ((size_t)b << 16) + (size_t)(kt64 * 16 + ml) * 64;
            if (q < 2) {
                half4_t fv = {(_Float16)(acc[0] * LOG2E), (_Float16)(acc[1] * LOG2E),
                              (_Float16)(acc[2] * LOG2E), (_Float16)(acc[3] * LOG2E)};
                *(half4_t*)(rec + q * 16 + t4 * 4) = fv;
            } else {
                // constant K-pad slots: q2 = {1,0,0,0}, q3 = zeros
                half4_t cv = (half4_t){};
                if (q == 2) cv[0] = (_Float16)1.0f;
                *(half4_t*)(rec + q * 16 + t4 * 4) = cv;
            }
            // g rows live in q>=2 lanes; gn2 via xor16 pairing (q2<->q3)
            float gn2p = acc[0] * acc[0] + acc[1] * acc[1] +
                         acc[2] * acc[2] + acc[3] * acc[3];
            float gn2 = gn2p + __shfl_xor(gn2p, 16, 64);
            if (q >= 2) {
                half4_t gv = {(_Float16)acc[0], (_Float16)acc[1],
                              (_Float16)acc[2], (_Float16)acc[3]};
                __half* gp = gT16 + (size_t)((b << 12) + gtok) * 16;
                *(half4_t*)(gp + (q - 2) * 4) = gv;
                if (q == 2) {
                    const float M = (LOG2E * 4.6f) * __builtin_sqrtf(gn2) + 1.0f;
                    *(half4_t*)(gp + 8) = (half4_t){(_Float16)(-M), 0, 0, 0};
                } else {
                    *(half4_t*)(gp + 12) = (half4_t){};
                }
            }
        } else {
            const int ch  = (w - 1) * 16 + q * 4;
            // paired-key layout position within the 64-half kt64 record
            const int pos = ((t4 >> 1) << 5) + ((ml >> 2) << 3) + ((t4 & 1) << 2) + (ml & 3);
            const size_t rowbase = ((size_t)(b * 64 + ch) << 12) + (size_t)kt64 * 64 + pos;
#pragma unroll
            for (int r = 0; r < 4; r++)
                hM[rowbase + ((size_t)r << 12)] = __float2half(acc[r]);
        }
    }
}

// ---------------- fused flash attention (key-split, shifted softmax) ---------
// grid (32 colblocks of 128, 8 b, S=8), block 256 = 4 waves x 32 cols.
// launch_bounds(256,8) forces VGPR<=64 -> 8 waves/SIMD resident.
// QK: 8x mfma 16x16x16 (interleaved in 2 pairs). PV: 16x mfma 16x16x32 with
// {even,odd}-group key-interleaved half8 frags. l: VALU adds + end shfl.
// h tiles: global_load_lds DMA, 2-buffer rotation, counted vmcnt(2).
#define PAIR(SEA, SOA, SEB, SOB, GOFF)                                          \
    {                                                                           \
        const _Float16* hp = hb + (GOFF);                                       \
        half8_t ah0 = *(const half8_t*)(hp);                                    \
        half8_t ah1 = *(const half8_t*)(hp + 1024);                             \
        float eA0 = fexp2(SEA[0]), eA1 = fexp2(SEA[1]),                         \
              eA2 = fexp2(SEA[2]), eA3 = fexp2(SEA[3]);                         \
        float oA0 = fexp2(SOA[0]), oA1 = fexp2(SOA[1]),                         \
              oA2 = fexp2(SOA[2]), oA3 = fexp2(SOA[3]);                         \
        float eB0 = fexp2(SEB[0]), eB1 = fexp2(SEB[1]),                         \
              eB2 = fexp2(SEB[2]), eB3 = fexp2(SEB[3]);                         \
        float oB0 = fexp2(SOB[0]), oB1 = fexp2(SOB[1]),                         \
              oB2 = fexp2(SOB[2]), oB3 = fexp2(SOB[3]);                         \
        lpA0 += (eA0 + eA1) + (eA2 + eA3);                                      \
        lpA1 += (oA0 + oA1) + (oA2 + oA3);                                      \
        lpB0 += (eB0 + eB1) + (eB2 + eB3);                                      \
        lpB1 += (oB0 + oB1) + (oB2 + oB3);                                      \
        half8_t ah2 = *(const half8_t*)(hp + 2048);                             \
        half8_t ah3 = *(const half8_t*)(hp + 3072);                             \
        half2_t eaA = pkcvt(eA0, eA1), ebA = pkcvt(eA2, eA3);                   \
        half2_t oaA = pkcvt(oA0, oA1), obA = pkcvt(oA2, oA3);                   \
        half2_t eaB = pkcvt(eB0, eB1), ebB = pkcvt(eB2, eB3);                   \
        half2_t oaB = pkcvt(oB0, oB1), obB = pkcvt(oB2, oB3);                   \
        half8_t pA8 = {eaA[0], eaA[1], ebA[0], ebA[1],                          \
                       oaA[0], oaA[1], obA[0], obA[1]};                         \
        half8_t pB8 = {eaB[0], eaB[1], ebB[0], ebB[1],                          \
                       oaB[0], oaB[1], obB[0], obB[1]};                         \
        __builtin_amdgcn_s_setprio(1);                                          \
        accA[0] = mfma32(ah0, pA8, accA[0]); accB[0] = mfma32(ah0, pB8, accB[0]); \
        accA[1] = mfma32(ah1, pA8, accA[1]); accB[1] = mfma32(ah1, pB8, accB[1]); \
        accA[2] = mfma32(ah2, pA8, accA[2]); accB[2] = mfma32(ah2, pB8, accB[2]); \
        accA[3] = mfma32(ah3, pA8, accA[3]); accB[3] = mfma32(ah3, pB8, accB[3]); \
        __builtin_amdgcn_s_setprio(0);                                          \
    }

template<int NT>
__global__ __launch_bounds__(256, 8) void attn_kernel(
    const __half* __restrict__ fTR, const __half* __restrict__ gT16,
    const __half* __restrict__ hM,
    __half* __restrict__ Pacc, float* __restrict__ Lsum)
{
    __shared__ __align__(16) _Float16 hl[2][4096];  // 2 x 8192 B, [ch][64]
    const int tid   = threadIdx.x;
    const int w     = tid >> 6;
    const int lane  = tid & 63;
    const int q     = lane >> 4;
    const int ml    = lane & 15;
    const int m7    = ml & 7;
    const int b     = blockIdx.y;
    const int split = blockIdx.z;
    const int colA  = blockIdx.x * 128 + w * 16 + ml;
    const int colB  = colA + 64;

    half4_t gfA = *(const half4_t*)(gT16 + ((size_t)((b << 12) + colA)) * 16 + q * 4);
    half4_t gfB = *(const half4_t*)(gT16 + ((size_t)((b << 12) + colB)) * 16 + q * 4);

    float4_t accA[4], accB[4];
#pragma unroll
    for (int cg = 0; cg < 4; cg++) {
        accA[cg] = (float4_t){0.f, 0.f, 0.f, 0.f};
        accB[cg] = (float4_t){0.f, 0.f, 0.f, 0.f};
    }
    float lpA0 = 0.f, lpA1 = 0.f, lpB0 = 0.f, lpB1 = 0.f;
    const float4_t z4 = (float4_t){0.f, 0.f, 0.f, 0.f};

    const int kt0 = split * NT;

    // DMA staging: lane-linear LDS dest (tid*16 B), XOR-swizzled global source.
    const int ch0  = tid >> 3;             // 0..31 (part0); part1 adds 32
    const int gsw  = (tid & 7) ^ (ch0 & 7);
    const __half* hs0 = hM + ((size_t)(b * 64 + ch0) << 12) + (size_t)kt0 * 64 + gsw * 8;
    const __half* hs1 = hs0 + ((size_t)32 << 12);
    const __half* fptr = fTR + ((size_t)b << 16) + (size_t)(kt0 * 16 + ml) * 64 + q * 16;

    // read-side swizzled group offsets (halves)
    const int gxa = ((q ^ m7) << 3);
    const int gxb = (((4 + q) ^ m7) << 3);

    // ---- prologue: DMA tile 0 + f record; full drain once ----
    GLDS(hs0, &hl[0][tid * 8]);
    GLDS(hs1, &hl[0][2048 + tid * 8]);
    half8_t f01 = *(const half8_t*)fptr;
    half8_t f23 = *(const half8_t*)(fptr + 8);
    __syncthreads();

#pragma unroll 1
    for (int kt = 0; kt < NT; kt++) {
        // ---- issue DMA for tile kt+1 first (vmcnt order: [G,G,f,f]) ----
        if (kt + 1 < NT) {
            _Float16* nb = &hl[(kt + 1) & 1][0];
            GLDS(hs0 + (kt + 1) * 64, nb + tid * 8);
            GLDS(hs1 + (kt + 1) * 64, nb + 2048 + tid * 8);
        }

        const _Float16* hb = &hl[kt & 1][ml << 6];
        half4_t afn0 = __builtin_shufflevector(f01, f01, 0, 1, 2, 3);
        half4_t afn1 = __builtin_shufflevector(f01, f01, 4, 5, 6, 7);
        half4_t afn2 = __builtin_shufflevector(f23, f23, 0, 1, 2, 3);
        half4_t afn3 = __builtin_shufflevector(f23, f23, 4, 5, 6, 7);

        // ---- QK pair 0 ----
        __builtin_amdgcn_s_setprio(1);
        float4_t stA0 = mfma16(afn0, gfA, z4);
        float4_t stB0 = mfma16(afn0, gfB, z4);
        float4_t stA1 = mfma16(afn1, gfA, z4);
        float4_t stB1 = mfma16(afn1, gfB, z4);
        __builtin_amdgcn_s_setprio(0);

        PAIR(stA0, stA1, stB0, stB1, gxa)

        // ---- QK pair 1 ----
        __builtin_amdgcn_s_setprio(1);
        float4_t stA2 = mfma16(afn2, gfA, z4);
        float4_t stB2 = mfma16(afn2, gfB, z4);
        float4_t stA3 = mfma16(afn3, gfA, z4);
        float4_t stB3 = mfma16(afn3, gfB, z4);
        __builtin_amdgcn_s_setprio(0);

        // ---- prefetch next f record ----
        if (kt + 1 < NT) {
            f01 = *(const half8_t*)(fptr + 1024);
            f23 = *(const half8_t*)(fptr + 1032);
            fptr += 1024;
        }

        PAIR(stA2, stA3, stB2, stB3, gxb)

        if (kt + 1 < NT) {
            WAITVM2_BAR();   // retires tile kt+1's DMA; f loads may stay in flight
        }
    }

    // ---- l: reduce lane-partial sums over q groups ----
    float lA = lpA0 + lpA1;
    lA += __shfl_xor(lA, 16, 64);
    lA += __shfl_xor(lA, 32, 64);
    float lB = lpB0 + lpB1;
    lB += __shfl_xor(lB, 16, 64);
    lB += __shfl_xor(lB, 32, 64);

    // ---- store UNNORMALIZED partials + l ----
    __half* pa = Pacc + (((size_t)(split * 8 + b) * 64) << 12);
#pragma unroll
    for (int cg = 0; cg < 4; cg++)
#pragma unroll
        for (int r = 0; r < 4; r++) {
            int ch = cg * 16 + q * 4 + r;
            pa[((size_t)ch << 12) + colA] = __float2half(accA[cg][r]);
            pa[((size_t)ch << 12) + colB] = __float2half(accB[cg][r]);
        }
    if (q == 0) {
        Lsum[((size_t)(split * 8 + b) << 12) + colA] = lA;
        Lsum[((size_t)(split * 8 + b) << 12) + colB] = lB;
    }
}

// ---------------- merge ------------------------------------------------------
// grid (64 col-tiles, 8 b, 4 ch-groups of 16), block 256 = 16 ch x 16 col-quads.
template<int S>
__global__ __launch_bounds__(256) void merge_kernel(
    const __half* __restrict__ Pacc, const float* __restrict__ Lsum,
    const float* __restrict__ x, const float* __restrict__ gammap,
    float* __restrict__ out)
{
    __shared__ float invL[64];
    const int tid  = threadIdx.x;
    const int c4   = tid & 15;
    const int chh  = tid >> 4;
    const int b    = blockIdx.y;
    const int col0 = blockIdx.x * 64;
    const int ch   = blockIdx.z * 16 + chh;

    if (tid < 64) {
        float L = 0.f;
#pragma unroll
        for (int s = 0; s < S; s++)
            L += Lsum[((size_t)(s * 8 + b) << 12) + col0 + tid];
        invL[tid] = gammap[0] / L;
    }
    __syncthreads();

    const int cc = c4 * 4;
    const size_t base = (((size_t)b * 64 + ch) << 12) + col0 + cc;
    float4 xv = *(const float4*)(x + base);
    float o0 = 0.f, o1 = 0.f, o2 = 0.f, o3 = 0.f;
#pragma unroll
    for (int s = 0; s < S; s++) {
        half4_t pv = *(const half4_t*)(Pacc +
            (((size_t)(s * 8 + b) * 64 + ch) << 12) + col0 + cc);
        o0 += (float)pv[0];
        o1 += (float)pv[1];
        o2 += (float)pv[2];
        o3 += (float)pv[3];
    }
    float4 ov;
    ov.x = o0 * invL[cc]     + xv.x;
    ov.y = o1 * invL[cc + 1] + xv.y;
    ov.z = o2 * invL[cc + 2] + xv.z;
    ov.w = o3 * invL[cc + 3] + xv.w;
    *(float4*)(out + base) = ov;
}

extern "C" void kernel_launch(void* const* d_in, const int* in_sizes, int n_in,
                              void* d_out, int out_size, void* d_ws, size_t ws_size,
                              hipStream_t stream) {
    const float* x     = (const float*)d_in[0];
    const float* Wq    = (const float*)d_in[1];
    const float* bq    = (const float*)d_in[2];
    const float* Wk    = (const float*)d_in[3];
    const float* bk    = (const float*)d_in[4];
    const float* Wv    = (const float*)d_in[5];
    const float* bv    = (const float*)d_in[6];
    const float* gamma = (const float*)d_in[7];
    float* out = (float*)d_out;

    const size_t fr_bytes  = (size_t)8 * 65536 * 2;             // 1 MB (fTR, 4 q-slots)
    const size_t g_bytes   = (size_t)8 * NTOK * 16 * 2;         // 1 MB
    const size_t hM_bytes  = (size_t)8 * 64 * NTOK * 2;         // 4 MB
    const size_t pa_split  = (size_t)8 * 64 * NTOK * 2;         // 4 MB per split
    const size_t l_split   = (size_t)8 * NTOK * sizeof(float);  // 128 KB per split
    const size_t base_need = fr_bytes + g_bytes + hM_bytes;

    int S = 1;
    if (ws_size >= base_need + 8 * (pa_split + l_split)) S = 8;
    else if (ws_size >= base_need + 4 * (pa_split + l_split)) S = 4;
    else if (ws_size >= base_need + 2 * (pa_split + l_split)) S = 2;

    char* p = (char*)d_ws;
    __half* fTR  = (__half*)p;  p += fr_bytes;
    __half* gT16 = (__half*)p;  p += g_bytes;
    __half* hM   = (__half*)p;  p += hM_bytes;
    __half* Pacc = (__half*)p;  p += (size_t)S * pa_split;
    float*  Lsum = (float*)p;

    proj_kernel<<<dim3(128, 8), 320, 0, stream>>>(x, Wq, bq, Wk, bk, Wv, bv,
                                                  fTR, gT16, hM);
    if (S == 8) {
        attn_kernel<8><<<dim3(32, 8, 8), 256, 0, stream>>>(fTR, gT16, hM, Pacc, Lsum);
        merge_kernel<8><<<dim3(64, 8, 4), 256, 0, stream>>>(Pacc, Lsum, x, gamma, out);
    } else if (S == 4) {
        attn_kernel<16><<<dim3(32, 8, 4), 256, 0, stream>>>(fTR, gT16, hM, Pacc, Lsum);
        merge_kernel<4><<<dim3(64, 8, 4), 256, 0, stream>>>(Pacc, Lsum, x, gamma, out);
    } else if (S == 2) {
        attn_kernel<32><<<dim3(32, 8, 2), 256, 0, stream>>>(fTR, gT16, hM, Pacc, Lsum);
        merge_kernel<2><<<dim3(64, 8, 4), 256, 0, stream>>>(Pacc, Lsum, x, gamma, out);
    } else {
        attn_kernel<64><<<dim3(32, 8, 1), 256, 0, stream>>>(fTR, gT16, hM, Pacc, Lsum);
        merge_kernel<1><<<dim3(64, 8, 4), 256, 0, stream>>>(Pacc, Lsum, x, gamma, out);
    }
}

// Round 5
// 128.908 us; speedup vs baseline: 3.3466x; 3.3466x over previous
//
#include <hip/hip_runtime.h>
#include <hip/hip_fp16.h>

// SelfAttention: B=8, C=64, N=4096, d_head=8.
// o[b,c,m] = gamma * sum_n h[b,c,n] * softmax_n(f[:,n].g[:,m]) + x[b,c,m]
// R18: single-column attn waves (16 cols/wave, was 32) so live state fits the
// 64-VGPR occupancy granule (m68/m69: granule ~64 -> 8 waves/SIMD only at
// <=64 VGPR; R17 proved occupancy follows VGPR but 2-col shape needs ~75 regs
// and spilled). Register census ~58: acc16 + gf2 + f8 + st8 + pk4 + lp2 +
// addr12. ah reads split 2+2 inside PAIR to cap transient pressure.
// Grid (64,8,4) = 2048 blocks = 8/CU; LDS 2x8KB -> 128KB/CU at 8 blocks.
// DMA staging + counted vmcnt(2) + 2-buffer rotation kept from R16.

typedef _Float16 half8_t __attribute__((ext_vector_type(8)));
typedef _Float16 half4_t __attribute__((ext_vector_type(4)));
typedef _Float16 half2_t __attribute__((ext_vector_type(2)));
typedef __fp16  fp16x2  __attribute__((ext_vector_type(2)));
typedef float float4_t __attribute__((ext_vector_type(4)));

#define NTOK 4096
#define PRH 72   // proj LDS row stride in halves
#define LOG2E 1.44269504088896340736f

#if __has_builtin(__builtin_amdgcn_exp2f)
__device__ __forceinline__ float fexp2(float x) { return __builtin_amdgcn_exp2f(x); }
#else
__device__ __forceinline__ float fexp2(float x) { return exp2f(x); }
#endif

__device__ __forceinline__ half2_t pkcvt(float a, float b) {
    fp16x2 v = __builtin_amdgcn_cvt_pkrtz(a, b);
    return __builtin_bit_cast(half2_t, v);
}

__device__ __forceinline__ float4_t mfma16(half4_t a, half4_t b, float4_t c) {
    return __builtin_amdgcn_mfma_f32_16x16x16f16(a, b, c, 0, 0, 0);
}
__device__ __forceinline__ float4_t mfma32(half8_t a, half8_t b, float4_t c) {
    return __builtin_amdgcn_mfma_f32_16x16x32_f16(a, b, c, 0, 0, 0);
}

#define GLDS(G, L) __builtin_amdgcn_global_load_lds(                            \
    (const __attribute__((address_space(1))) unsigned int*)(G),                 \
    (__attribute__((address_space(3))) unsigned int*)(L), 16, 0, 0)

// counted wait + raw barrier: tile DMA (issued first this iter) retired,
// f-record loads (issued after) may stay in flight
#define WAITVM2_BAR() do {                                                      \
    __builtin_amdgcn_sched_barrier(0);                                          \
    asm volatile("s_waitcnt vmcnt(2)" ::: "memory");                            \
    __builtin_amdgcn_sched_barrier(0);                                          \
    __builtin_amdgcn_s_barrier();                                               \
} while (0)

// ---------------- projection (MFMA) ------------------------------------------
// grid (128 token-tiles of 32, 8 b), block 320 = 5 waves = 5 out-row-groups.
// wave0 rows = Wq(8)+Wk(8); waves1-4 = Wv rows. x staged transposed to LDS
// fp16 with XOR channel swizzle. fTR records: [b][kt64*16+ml][q][t4][4] halves;
// q>=2 slots are the K-pad constants. hM stored PAIRED:
// hM[b][ch][kt64][pos] with pos = (t4>>1)*32 + (ml>>2)*8 + (t4&1)*4 + (ml&3)
// (key = kt64*64 + t4*16 + ml), so attn PV A-frags are contiguous b128.
__global__ __launch_bounds__(320) void proj_kernel(
    const float* __restrict__ x,
    const float* __restrict__ Wq, const float* __restrict__ bq,
    const float* __restrict__ Wk, const float* __restrict__ bk,
    const float* __restrict__ Wv, const float* __restrict__ bv,
    __half* __restrict__ fTR, __half* __restrict__ gT16, __half* __restrict__ hM)
{
    __shared__ __align__(16) _Float16 xh[32 * PRH];   // 4.6 KB
    const int t      = threadIdx.x;
    const int blk    = blockIdx.x;
    const int b      = blockIdx.y;
    const int n0     = blk * 32;
    const int kt64   = blk >> 1;
    const int t4base = (blk & 1) * 2;

    // stage x[b][c][n0..+31] -> xh[tok][c ^ swz] fp16
    if (t < 256) {
#pragma unroll
        for (int i = 0; i < 2; i++) {
            const int idx = t + i * 256;
            const int c = idx >> 3, f4 = idx & 7;          // tokens f4*4..+3
            float4 v = *(const float4*)(x + (((size_t)(b * 64 + c)) << 12) + n0 + f4 * 4);
            const int cs = c ^ ((f4 & 3) << 4);
            xh[(f4 * 4 + 0) * PRH + cs] = (_Float16)v.x;
            xh[(f4 * 4 + 1) * PRH + cs] = (_Float16)v.y;
            xh[(f4 * 4 + 2) * PRH + cs] = (_Float16)v.z;
            xh[(f4 * 4 + 3) * PRH + cs] = (_Float16)v.w;
        }
    }

    const int w    = t >> 6;
    const int lane = t & 63;
    const int q    = lane >> 4;
    const int ml   = lane & 15;

    // A-frags: W row, k = ks*16 + q*4 + j
    const float* wrow;
    if (w == 0) wrow = (ml < 8) ? (Wq + ml * 64) : (Wk + (ml - 8) * 64);
    else        wrow = Wv + ((w - 1) * 16 + ml) * 64;
    half4_t afr[4];
#pragma unroll
    for (int ks = 0; ks < 4; ks++) {
        float4 wv4 = *(const float4*)(wrow + ks * 16 + q * 4);
        afr[ks] = (half4_t){(_Float16)wv4.x, (_Float16)wv4.y,
                            (_Float16)wv4.z, (_Float16)wv4.w};
    }
    float4 bias4;
    if (w == 0) bias4 = (q < 2) ? *(const float4*)(bq + q * 4)
                                : *(const float4*)(bk + (q - 2) * 4);
    else        bias4 = *(const float4*)(bv + (w - 1) * 16 + q * 4);

    __syncthreads();

#pragma unroll
    for (int cg = 0; cg < 2; cg++) {
        const int tok  = cg * 16 + ml;                  // local token
        const int swz  = (tok >> 2) & 3;
        float4_t acc = (float4_t){0.f, 0.f, 0.f, 0.f};
#pragma unroll
        for (int ks = 0; ks < 4; ks++) {
            half4_t bfr = *(const half4_t*)(&xh[tok * PRH + ((ks ^ swz) * 16 + q * 4)]);
            acc = __builtin_amdgcn_mfma_f32_16x16x16f16(afr[ks], bfr, acc, 0, 0, 0);
        }
        acc[0] += bias4.x; acc[1] += bias4.y; acc[2] += bias4.z; acc[3] += bias4.w;
        const int gtok = n0 + tok;
        const int t4   = t4base + cg;

        if (w == 0) {
            __half* rec = fTR + ((size_t)b << 16) + (size_t)(kt64 * 16 + ml) * 64;
            if (q < 2) {
                half4_t fv = {(_Float16)(acc[0] * LOG2E), (_Float16)(acc[1] * LOG2E),
                              (_Float16)(acc[2] * LOG2E), (_Float16)(acc[3] * LOG2E)};
                *(half4_t*)(rec + q * 16 + t4 * 4) = fv;
            } else {
                // constant K-pad slots: q2 = {1,0,0,0}, q3 = zeros
                half4_t cv = (half4_t){};
                if (q == 2) cv[0] = (_Float16)1.0f;
                *(half4_t*)(rec + q * 16 + t4 * 4) = cv;
            }
            // g rows live in q>=2 lanes; gn2 via xor16 pairing (q2<->q3)
            float gn2p = acc[0] * acc[0] + acc[1] * acc[1] +
                         acc[2] * acc[2] + acc[3] * acc[3];
            float gn2 = gn2p + __shfl_xor(gn2p, 16, 64);
            if (q >= 2) {
                half4_t gv = {(_Float16)acc[0], (_Float16)acc[1],
                              (_Float16)acc[2], (_Float16)acc[3]};
                __half* gp = gT16 + (size_t)((b << 12) + gtok) * 16;
                *(half4_t*)(gp + (q - 2) * 4) = gv;
                if (q == 2) {
                    const float M = (LOG2E * 4.6f) * __builtin_sqrtf(gn2) + 1.0f;
                    *(half4_t*)(gp + 8) = (half4_t){(_Float16)(-M), 0, 0, 0};
                } else {
                    *(half4_t*)(gp + 12) = (half4_t){};
                }
            }
        } else {
            const int ch  = (w - 1) * 16 + q * 4;
            // paired-key layout position within the 64-half kt64 record
            const int pos = ((t4 >> 1) << 5) + ((ml >> 2) << 3) + ((t4 & 1) << 2) + (ml & 3);
            const size_t rowbase = ((size_t)(b * 64 + ch) << 12) + (size_t)kt64 * 64 + pos;
#pragma unroll
            for (int r = 0; r < 4; r++)
                hM[rowbase + ((size_t)r << 12)] = __float2half(acc[r]);
        }
    }
}

// ---------------- fused flash attention (key-split, shifted softmax) ---------
// grid (64 colblocks of 64, 8 b, S), block 256 = 4 waves x 16 cols each.
// Single column-tile per wave -> ~58 live VGPR -> 8 waves/SIMD resident.
// QK: 4x mfma 16x16x16. PV: 8x mfma 16x16x32 ({even,odd} key-interleaved
// half8 frags). l: VALU adds + end shfl. 2-buffer DMA staging, vmcnt(2).
#define PAIR1(SE, SO, GOFF)                                                     \
    {                                                                           \
        const _Float16* hp = hb + (GOFF);                                       \
        float e0 = fexp2(SE[0]), e1 = fexp2(SE[1]),                             \
              e2 = fexp2(SE[2]), e3 = fexp2(SE[3]);                             \
        float o0 = fexp2(SO[0]), o1 = fexp2(SO[1]),                             \
              o2 = fexp2(SO[2]), o3 = fexp2(SO[3]);                             \
        lp0 += (e0 + e1) + (e2 + e3);                                           \
        lp1 += (o0 + o1) + (o2 + o3);                                           \
        half2_t ea = pkcvt(e0, e1), eb = pkcvt(e2, e3);                         \
        half2_t oa = pkcvt(o0, o1), ob = pkcvt(o2, o3);                         \
        half8_t p8 = {ea[0], ea[1], eb[0], eb[1],                               \
                      oa[0], oa[1], ob[0], ob[1]};                              \
        half8_t ah0 = *(const half8_t*)(hp);                                    \
        half8_t ah1 = *(const half8_t*)(hp + 1024);                             \
        __builtin_amdgcn_s_setprio(1);                                          \
        acc[0] = mfma32(ah0, p8, acc[0]);                                       \
        acc[1] = mfma32(ah1, p8, acc[1]);                                       \
        __builtin_amdgcn_s_setprio(0);                                          \
        half8_t ah2 = *(const half8_t*)(hp + 2048);                             \
        half8_t ah3 = *(const half8_t*)(hp + 3072);                             \
        __builtin_amdgcn_s_setprio(1);                                          \
        acc[2] = mfma32(ah2, p8, acc[2]);                                       \
        acc[3] = mfma32(ah3, p8, acc[3]);                                       \
        __builtin_amdgcn_s_setprio(0);                                          \
    }

template<int NT>
__global__ __launch_bounds__(256, 8) void attn_kernel(
    const __half* __restrict__ fTR, const __half* __restrict__ gT16,
    const __half* __restrict__ hM,
    __half* __restrict__ Pacc, float* __restrict__ Lsum)
{
    __shared__ __align__(16) _Float16 hl[2][4096];  // 2 x 8192 B, [ch][64]
    const int tid   = threadIdx.x;
    const int w     = tid >> 6;
    const int lane  = tid & 63;
    const int q     = lane >> 4;
    const int ml    = lane & 15;
    const int m7    = ml & 7;
    const int b     = blockIdx.y;
    const int split = blockIdx.z;
    const int colA  = blockIdx.x * 64 + w * 16 + ml;

    half4_t gfA = *(const half4_t*)(gT16 + ((size_t)((b << 12) + colA)) * 16 + q * 4);

    float4_t acc[4];
#pragma unroll
    for (int cg = 0; cg < 4; cg++)
        acc[cg] = (float4_t){0.f, 0.f, 0.f, 0.f};
    float lp0 = 0.f, lp1 = 0.f;
    const float4_t z4 = (float4_t){0.f, 0.f, 0.f, 0.f};

    const int kt0 = split * NT;

    // DMA staging: lane-linear LDS dest (tid*16 B), XOR-swizzled global source.
    const int ch0  = tid >> 3;             // 0..31 (part0); part1 adds 32
    const int gsw  = (tid & 7) ^ (ch0 & 7);
    const __half* hs0 = hM + ((size_t)(b * 64 + ch0) << 12) + (size_t)kt0 * 64 + gsw * 8;
    const __half* hs1 = hs0 + ((size_t)32 << 12);
    const __half* fptr = fTR + ((size_t)b << 16) + (size_t)(kt0 * 16 + ml) * 64 + q * 16;

    // read-side swizzled group offsets (halves)
    const int gxa = ((q ^ m7) << 3);
    const int gxb = (((4 + q) ^ m7) << 3);

    // ---- prologue: DMA tile 0 + f record; full drain once ----
    GLDS(hs0, &hl[0][tid * 8]);
    GLDS(hs1, &hl[0][2048 + tid * 8]);
    half8_t f01 = *(const half8_t*)fptr;
    half8_t f23 = *(const half8_t*)(fptr + 8);
    __syncthreads();

#pragma unroll 1
    for (int kt = 0; kt < NT; kt++) {
        // ---- issue DMA for tile kt+1 first (vmcnt order: [G,G,f,f]) ----
        if (kt + 1 < NT) {
            _Float16* nb = &hl[(kt + 1) & 1][0];
            GLDS(hs0 + (kt + 1) * 64, nb + tid * 8);
            GLDS(hs1 + (kt + 1) * 64, nb + 2048 + tid * 8);
        }

        const _Float16* hb = &hl[kt & 1][ml << 6];
        half4_t afn0 = __builtin_shufflevector(f01, f01, 0, 1, 2, 3);
        half4_t afn1 = __builtin_shufflevector(f01, f01, 4, 5, 6, 7);

        // ---- QK pair 0 ----
        __builtin_amdgcn_s_setprio(1);
        float4_t st0 = mfma16(afn0, gfA, z4);
        float4_t st1 = mfma16(afn1, gfA, z4);
        __builtin_amdgcn_s_setprio(0);

        PAIR1(st0, st1, gxa)

        half4_t afn2 = __builtin_shufflevector(f23, f23, 0, 1, 2, 3);
        half4_t afn3 = __builtin_shufflevector(f23, f23, 4, 5, 6, 7);

        // ---- QK pair 1 ----
        __builtin_amdgcn_s_setprio(1);
        float4_t st2 = mfma16(afn2, gfA, z4);
        float4_t st3 = mfma16(afn3, gfA, z4);
        __builtin_amdgcn_s_setprio(0);

        // ---- prefetch next f record (after f23 consumed) ----
        if (kt + 1 < NT) {
            f01 = *(const half8_t*)(fptr + 1024);
            f23 = *(const half8_t*)(fptr + 1032);
            fptr += 1024;
        }

        PAIR1(st2, st3, gxb)

        if (kt + 1 < NT) {
            WAITVM2_BAR();   // retires tile kt+1's DMA; f loads may stay in flight
        }
    }

    // ---- l: reduce lane-partial sums over q groups ----
    float lA = lp0 + lp1;
    lA += __shfl_xor(lA, 16, 64);
    lA += __shfl_xor(lA, 32, 64);

    // ---- store UNNORMALIZED partials + l ----
    __half* pa = Pacc + (((size_t)(split * 8 + b) * 64) << 12);
#pragma unroll
    for (int cg = 0; cg < 4; cg++)
#pragma unroll
        for (int r = 0; r < 4; r++) {
            int ch = cg * 16 + q * 4 + r;
            pa[((size_t)ch << 12) + colA] = __float2half(acc[cg][r]);
        }
    if (q == 0)
        Lsum[((size_t)(split * 8 + b) << 12) + colA] = lA;
}

// ---------------- merge ------------------------------------------------------
// grid (64 col-tiles, 8 b, 4 ch-groups of 16), block 256 = 16 ch x 16 col-quads.
template<int S>
__global__ __launch_bounds__(256) void merge_kernel(
    const __half* __restrict__ Pacc, const float* __restrict__ Lsum,
    const float* __restrict__ x, const float* __restrict__ gammap,
    float* __restrict__ out)
{
    __shared__ float invL[64];
    const int tid  = threadIdx.x;
    const int c4   = tid & 15;
    const int chh  = tid >> 4;
    const int b    = blockIdx.y;
    const int col0 = blockIdx.x * 64;
    const int ch   = blockIdx.z * 16 + chh;

    if (tid < 64) {
        float L = 0.f;
#pragma unroll
        for (int s = 0; s < S; s++)
            L += Lsum[((size_t)(s * 8 + b) << 12) + col0 + tid];
        invL[tid] = gammap[0] / L;
    }
    __syncthreads();

    const int cc = c4 * 4;
    const size_t base = (((size_t)b * 64 + ch) << 12) + col0 + cc;
    float4 xv = *(const float4*)(x + base);
    float o0 = 0.f, o1 = 0.f, o2 = 0.f, o3 = 0.f;
#pragma unroll
    for (int s = 0; s < S; s++) {
        half4_t pv = *(const half4_t*)(Pacc +
            (((size_t)(s * 8 + b) * 64 + ch) << 12) + col0 + cc);
        o0 += (float)pv[0];
        o1 += (float)pv[1];
        o2 += (float)pv[2];
        o3 += (float)pv[3];
    }
    float4 ov;
    ov.x = o0 * invL[cc]     + xv.x;
    ov.y = o1 * invL[cc + 1] + xv.y;
    ov.z = o2 * invL[cc + 2] + xv.z;
    ov.w = o3 * invL[cc + 3] + xv.w;
    *(float4*)(out + base) = ov;
}

extern "C" void kernel_launch(void* const* d_in, const int* in_sizes, int n_in,
                              void* d_out, int out_size, void* d_ws, size_t ws_size,
                              hipStream_t stream) {
    const float* x     = (const float*)d_in[0];
    const float* Wq    = (const float*)d_in[1];
    const float* bq    = (const float*)d_in[2];
    const float* Wk    = (const float*)d_in[3];
    const float* bk    = (const float*)d_in[4];
    const float* Wv    = (const float*)d_in[5];
    const float* bv    = (const float*)d_in[6];
    const float* gamma = (const float*)d_in[7];
    float* out = (float*)d_out;

    const size_t fr_bytes  = (size_t)8 * 65536 * 2;             // 1 MB (fTR, 4 q-slots)
    const size_t g_bytes   = (size_t)8 * NTOK * 16 * 2;         // 1 MB
    const size_t hM_bytes  = (size_t)8 * 64 * NTOK * 2;         // 4 MB
    const size_t pa_split  = (size_t)8 * 64 * NTOK * 2;         // 4 MB per split
    const size_t l_split   = (size_t)8 * NTOK * sizeof(float);  // 128 KB per split
    const size_t base_need = fr_bytes + g_bytes + hM_bytes;

    int S = 1;
    if (ws_size >= base_need + 4 * (pa_split + l_split)) S = 4;
    else if (ws_size >= base_need + 2 * (pa_split + l_split)) S = 2;

    char* p = (char*)d_ws;
    __half* fTR  = (__half*)p;  p += fr_bytes;
    __half* gT16 = (__half*)p;  p += g_bytes;
    __half* hM   = (__half*)p;  p += hM_bytes;
    __half* Pacc = (__half*)p;  p += (size_t)S * pa_split;
    float*  Lsum = (float*)p;

    proj_kernel<<<dim3(128, 8), 320, 0, stream>>>(x, Wq, bq, Wk, bk, Wv, bv,
                                                  fTR, gT16, hM);
    if (S == 4) {
        attn_kernel<16><<<dim3(64, 8, 4), 256, 0, stream>>>(fTR, gT16, hM, Pacc, Lsum);
        merge_kernel<4><<<dim3(64, 8, 4), 256, 0, stream>>>(Pacc, Lsum, x, gamma, out);
    } else if (S == 2) {
        attn_kernel<32><<<dim3(64, 8, 2), 256, 0, stream>>>(fTR, gT16, hM, Pacc, Lsum);
        merge_kernel<2><<<dim3(64, 8, 4), 256, 0, stream>>>(Pacc, Lsum, x, gamma, out);
    } else {
        attn_kernel<64><<<dim3(64, 8, 1), 256, 0, stream>>>(fTR, gT16, hM, Pacc, Lsum);
        merge_kernel<1><<<dim3(64, 8, 4), 256, 0, stream>>>(Pacc, Lsum, x, gamma, out);
    }
}

// Round 6
// 116.496 us; speedup vs baseline: 3.7032x; 1.1065x over previous
//
#include <hip/hip_runtime.h>
#include <hip/hip_fp16.h>

// SelfAttention: B=8, C=64, N=4096, d_head=8.
// o[b,c,m] = gamma * sum_n h[b,c,n] * softmax_n(f[:,n].g[:,m]) + x[b,c,m]
// R19: back to the 2-col R16 shape (best measured; R18 proved occupancy is
// not the limiter) with BK=128 keys per iteration: half the barriers/vmcnt
// waits/DMA-issue events at identical bytes+math. vmcnt(4) counted wait
// (4 GLDS retired, 4 f-loads in flight across the barrier). p8 packed via
// uint4 bit-cast (register concat, no v_perm). 2x16KB LDS buffers.

typedef _Float16 half8_t __attribute__((ext_vector_type(8)));
typedef _Float16 half4_t __attribute__((ext_vector_type(4)));
typedef _Float16 half2_t __attribute__((ext_vector_type(2)));
typedef __fp16  fp16x2  __attribute__((ext_vector_type(2)));
typedef float float4_t __attribute__((ext_vector_type(4)));
typedef unsigned int uintx4 __attribute__((ext_vector_type(4)));

#define NTOK 4096
#define PRH 72   // proj LDS row stride in halves
#define LOG2E 1.44269504088896340736f

#if __has_builtin(__builtin_amdgcn_exp2f)
__device__ __forceinline__ float fexp2(float x) { return __builtin_amdgcn_exp2f(x); }
#else
__device__ __forceinline__ float fexp2(float x) { return exp2f(x); }
#endif

__device__ __forceinline__ half2_t pkcvt(float a, float b) {
    fp16x2 v = __builtin_amdgcn_cvt_pkrtz(a, b);
    return __builtin_bit_cast(half2_t, v);
}

__device__ __forceinline__ float4_t mfma16(half4_t a, half4_t b, float4_t c) {
    return __builtin_amdgcn_mfma_f32_16x16x16f16(a, b, c, 0, 0, 0);
}
__device__ __forceinline__ float4_t mfma32(half8_t a, half8_t b, float4_t c) {
    return __builtin_amdgcn_mfma_f32_16x16x32_f16(a, b, c, 0, 0, 0);
}

#define GLDS(G, L) __builtin_amdgcn_global_load_lds(                            \
    (const __attribute__((address_space(1))) unsigned int*)(G),                 \
    (__attribute__((address_space(3))) unsigned int*)(L), 16, 0, 0)

// counted wait + raw barrier: the 4 tile-DMAs (issued first this iter) are
// retired; the 4 f-record loads (issued after) may stay in flight
#define WAITVM4_BAR() do {                                                      \
    __builtin_amdgcn_sched_barrier(0);                                          \
    asm volatile("s_waitcnt vmcnt(4)" ::: "memory");                            \
    __builtin_amdgcn_sched_barrier(0);                                          \
    __builtin_amdgcn_s_barrier();                                               \
} while (0)

// ---------------- projection (MFMA) ------------------------------------------
// grid (128 token-tiles of 32, 8 b), block 320 = 5 waves = 5 out-row-groups.
// wave0 rows = Wq(8)+Wk(8); waves1-4 = Wv rows. x staged transposed to LDS
// fp16 with XOR channel swizzle. fTR records: [b][kt64*16+ml][q][t4][4] halves;
// q>=2 slots are the K-pad constants. hM stored PAIRED:
// hM[b][ch][kt64][pos] with pos = (t4>>1)*32 + (ml>>2)*8 + (t4&1)*4 + (ml&3)
// (key = kt64*64 + t4*16 + ml), so attn PV A-frags are contiguous b128.
__global__ __launch_bounds__(320) void proj_kernel(
    const float* __restrict__ x,
    const float* __restrict__ Wq, const float* __restrict__ bq,
    const float* __restrict__ Wk, const float* __restrict__ bk,
    const float* __restrict__ Wv, const float* __restrict__ bv,
    __half* __restrict__ fTR, __half* __restrict__ gT16, __half* __restrict__ hM)
{
    __shared__ __align__(16) _Float16 xh[32 * PRH];   // 4.6 KB
    const int t      = threadIdx.x;
    const int blk    = blockIdx.x;
    const int b      = blockIdx.y;
    const int n0     = blk * 32;
    const int kt64   = blk >> 1;
    const int t4base = (blk & 1) * 2;

    // stage x[b][c][n0..+31] -> xh[tok][c ^ swz] fp16
    if (t < 256) {
#pragma unroll
        for (int i = 0; i < 2; i++) {
            const int idx = t + i * 256;
            const int c = idx >> 3, f4 = idx & 7;          // tokens f4*4..+3
            float4 v = *(const float4*)(x + (((size_t)(b * 64 + c)) << 12) + n0 + f4 * 4);
            const int cs = c ^ ((f4 & 3) << 4);
            xh[(f4 * 4 + 0) * PRH + cs] = (_Float16)v.x;
            xh[(f4 * 4 + 1) * PRH + cs] = (_Float16)v.y;
            xh[(f4 * 4 + 2) * PRH + cs] = (_Float16)v.z;
            xh[(f4 * 4 + 3) * PRH + cs] = (_Float16)v.w;
        }
    }

    const int w    = t >> 6;
    const int lane = t & 63;
    const int q    = lane >> 4;
    const int ml   = lane & 15;

    // A-frags: W row, k = ks*16 + q*4 + j
    const float* wrow;
    if (w == 0) wrow = (ml < 8) ? (Wq + ml * 64) : (Wk + (ml - 8) * 64);
    else        wrow = Wv + ((w - 1) * 16 + ml) * 64;
    half4_t afr[4];
#pragma unroll
    for (int ks = 0; ks < 4; ks++) {
        float4 wv4 = *(const float4*)(wrow + ks * 16 + q * 4);
        afr[ks] = (half4_t){(_Float16)wv4.x, (_Float16)wv4.y,
                            (_Float16)wv4.z, (_Float16)wv4.w};
    }
    float4 bias4;
    if (w == 0) bias4 = (q < 2) ? *(const float4*)(bq + q * 4)
                                : *(const float4*)(bk + (q - 2) * 4);
    else        bias4 = *(const float4*)(bv + (w - 1) * 16 + q * 4);

    __syncthreads();

#pragma unroll
    for (int cg = 0; cg < 2; cg++) {
        const int tok  = cg * 16 + ml;                  // local token
        const int swz  = (tok >> 2) & 3;
        float4_t acc = (float4_t){0.f, 0.f, 0.f, 0.f};
#pragma unroll
        for (int ks = 0; ks < 4; ks++) {
            half4_t bfr = *(const half4_t*)(&xh[tok * PRH + ((ks ^ swz) * 16 + q * 4)]);
            acc = __builtin_amdgcn_mfma_f32_16x16x16f16(afr[ks], bfr, acc, 0, 0, 0);
        }
        acc[0] += bias4.x; acc[1] += bias4.y; acc[2] += bias4.z; acc[3] += bias4.w;
        const int gtok = n0 + tok;
        const int t4   = t4base + cg;

        if (w == 0) {
            __half* rec = fTR + ((size_t)b << 16) + (size_t)(kt64 * 16 + ml) * 64;
            if (q < 2) {
                half4_t fv = {(_Float16)(acc[0] * LOG2E), (_Float16)(acc[1] * LOG2E),
                              (_Float16)(acc[2] * LOG2E), (_Float16)(acc[3] * LOG2E)};
                *(half4_t*)(rec + q * 16 + t4 * 4) = fv;
            } else {
                // constant K-pad slots: q2 = {1,0,0,0}, q3 = zeros
                half4_t cv = (half4_t){};
                if (q == 2) cv[0] = (_Float16)1.0f;
                *(half4_t*)(rec + q * 16 + t4 * 4) = cv;
            }
            // g rows live in q>=2 lanes; gn2 via xor16 pairing (q2<->q3)
            float gn2p = acc[0] * acc[0] + acc[1] * acc[1] +
                         acc[2] * acc[2] + acc[3] * acc[3];
            float gn2 = gn2p + __shfl_xor(gn2p, 16, 64);
            if (q >= 2) {
                half4_t gv = {(_Float16)acc[0], (_Float16)acc[1],
                              (_Float16)acc[2], (_Float16)acc[3]};
                __half* gp = gT16 + (size_t)((b << 12) + gtok) * 16;
                *(half4_t*)(gp + (q - 2) * 4) = gv;
                if (q == 2) {
                    const float M = (LOG2E * 4.6f) * __builtin_sqrtf(gn2) + 1.0f;
                    *(half4_t*)(gp + 8) = (half4_t){(_Float16)(-M), 0, 0, 0};
                } else {
                    *(half4_t*)(gp + 12) = (half4_t){};
                }
            }
        } else {
            const int ch  = (w - 1) * 16 + q * 4;
            // paired-key layout position within the 64-half kt64 record
            const int pos = ((t4 >> 1) << 5) + ((ml >> 2) << 3) + ((t4 & 1) << 2) + (ml & 3);
            const size_t rowbase = ((size_t)(b * 64 + ch) << 12) + (size_t)kt64 * 64 + pos;
#pragma unroll
            for (int r = 0; r < 4; r++)
                hM[rowbase + ((size_t)r << 12)] = __float2half(acc[r]);
        }
    }
}

// ---------------- fused flash attention (key-split, shifted softmax) ---------
// grid (32 colblocks of 128, 8 b, S), block 256 = 4 waves x 32 cols (2 tiles).
// BK=128 keys/iter = two 64-key groups; NT=8 iters at S=4. Per iter:
// 16 QK mfma16 + 8 ones-l mfma32 + 32 PV mfma32, one barrier, 4 GLDS DMA,
// 4 f b128 loads. vmcnt(4) counted wait. XOR-by-(ch&7) swizzle on global
// source + read offset. p8 via uint4 bit-cast concat (no v_perm).
#define PAIR(SEA, SOA, SEB, SOB, HB, GOFF)                                      \
    {                                                                           \
        const _Float16* hp = (HB) + (GOFF);                                     \
        half8_t ah0 = *(const half8_t*)(hp);                                    \
        half8_t ah1 = *(const half8_t*)(hp + 1024);                             \
        half8_t ah2 = *(const half8_t*)(hp + 2048);                             \
        half8_t ah3 = *(const half8_t*)(hp + 3072);                             \
        float eA0 = fexp2(SEA[0]), eA1 = fexp2(SEA[1]),                         \
              eA2 = fexp2(SEA[2]), eA3 = fexp2(SEA[3]);                         \
        float oA0 = fexp2(SOA[0]), oA1 = fexp2(SOA[1]),                         \
              oA2 = fexp2(SOA[2]), oA3 = fexp2(SOA[3]);                         \
        float eB0 = fexp2(SEB[0]), eB1 = fexp2(SEB[1]),                         \
              eB2 = fexp2(SEB[2]), eB3 = fexp2(SEB[3]);                         \
        float oB0 = fexp2(SOB[0]), oB1 = fexp2(SOB[1]),                         \
              oB2 = fexp2(SOB[2]), oB3 = fexp2(SOB[3]);                         \
        uintx4 puA = {__builtin_bit_cast(unsigned int, pkcvt(eA0, eA1)),        \
                      __builtin_bit_cast(unsigned int, pkcvt(eA2, eA3)),        \
                      __builtin_bit_cast(unsigned int, pkcvt(oA0, oA1)),        \
                      __builtin_bit_cast(unsigned int, pkcvt(oA2, oA3))};       \
        uintx4 puB = {__builtin_bit_cast(unsigned int, pkcvt(eB0, eB1)),        \
                      __builtin_bit_cast(unsigned int, pkcvt(eB2, eB3)),        \
                      __builtin_bit_cast(unsigned int, pkcvt(oB0, oB1)),        \
                      __builtin_bit_cast(unsigned int, pkcvt(oB2, oB3))};       \
        half8_t pA8 = __builtin_bit_cast(half8_t, puA);                         \
        half8_t pB8 = __builtin_bit_cast(half8_t, puB);                         \
        __builtin_amdgcn_s_setprio(1);                                          \
        accLA = mfma32(ones8, pA8, accLA);                                      \
        accLB = mfma32(ones8, pB8, accLB);                                      \
        accA[0] = mfma32(ah0, pA8, accA[0]); accB[0] = mfma32(ah0, pB8, accB[0]); \
        accA[1] = mfma32(ah1, pA8, accA[1]); accB[1] = mfma32(ah1, pB8, accB[1]); \
        accA[2] = mfma32(ah2, pA8, accA[2]); accB[2] = mfma32(ah2, pB8, accB[2]); \
        accA[3] = mfma32(ah3, pA8, accA[3]); accB[3] = mfma32(ah3, pB8, accB[3]); \
        __builtin_amdgcn_s_setprio(0);                                          \
    }

template<int NT>
__global__ __launch_bounds__(256) void attn_kernel(
    const __half* __restrict__ fTR, const __half* __restrict__ gT16,
    const __half* __restrict__ hM,
    __half* __restrict__ Pacc, float* __restrict__ Lsum)
{
    __shared__ __align__(16) _Float16 hl[2][8192];  // 2 x 16 KB, [group][ch][64]
    const int tid   = threadIdx.x;
    const int w     = tid >> 6;
    const int lane  = tid & 63;
    const int q     = lane >> 4;
    const int ml    = lane & 15;
    const int m7    = ml & 7;
    const int b     = blockIdx.y;
    const int split = blockIdx.z;
    const int colA  = blockIdx.x * 128 + w * 16 + ml;
    const int colB  = colA + 64;

    half4_t gfA = *(const half4_t*)(gT16 + ((size_t)((b << 12) + colA)) * 16 + q * 4);
    half4_t gfB = *(const half4_t*)(gT16 + ((size_t)((b << 12) + colB)) * 16 + q * 4);

    float4_t accA[4], accB[4];
#pragma unroll
    for (int cg = 0; cg < 4; cg++) {
        accA[cg] = (float4_t){0.f, 0.f, 0.f, 0.f};
        accB[cg] = (float4_t){0.f, 0.f, 0.f, 0.f};
    }
    float4_t accLA = (float4_t){0.f, 0.f, 0.f, 0.f};
    float4_t accLB = (float4_t){0.f, 0.f, 0.f, 0.f};
    const half8_t ones8 = {(_Float16)1.0f, (_Float16)1.0f, (_Float16)1.0f,
                           (_Float16)1.0f, (_Float16)1.0f, (_Float16)1.0f,
                           (_Float16)1.0f, (_Float16)1.0f};
    const float4_t z4 = (float4_t){0.f, 0.f, 0.f, 0.f};

    const int k64 = split * NT * 2;        // first 64-key group index

    // DMA staging: lane-linear LDS dest (tid*16 B), XOR-swizzled global source.
    const int ch0  = tid >> 3;             // 0..31 (part0); part1 adds 32
    const int gsw  = (tid & 7) ^ (ch0 & 7);
    const __half* hs0 = hM + ((size_t)(b * 64 + ch0) << 12) + (size_t)k64 * 64 + gsw * 8;
    const __half* hs1 = hs0 + ((size_t)32 << 12);
    const __half* fptr = fTR + ((size_t)b << 16) + (size_t)(k64 * 16 + ml) * 64 + q * 16;

    // read-side swizzled group offsets (halves)
    const int gxa = ((q ^ m7) << 3);
    const int gxb = (((4 + q) ^ m7) << 3);

    // ---- prologue: DMA 128-key tile 0 + both f records; full drain once ----
    GLDS(hs0,      &hl[0][tid * 8]);
    GLDS(hs1,      &hl[0][2048 + tid * 8]);
    GLDS(hs0 + 64, &hl[0][4096 + tid * 8]);
    GLDS(hs1 + 64, &hl[0][6144 + tid * 8]);
    half8_t f01 = *(const half8_t*)fptr;
    half8_t f23 = *(const half8_t*)(fptr + 8);
    half8_t f45 = *(const half8_t*)(fptr + 1024);
    half8_t f67 = *(const half8_t*)(fptr + 1032);
    __syncthreads();

    const __half* hn0 = hs0 + 128;
    const __half* hn1 = hs1 + 128;

#pragma unroll 1
    for (int kt = 0; kt < NT; kt++) {
        // ---- issue 4 GLDS for tile kt+1 first (vmcnt order: [G x4][f x4]) ----
        if (kt + 1 < NT) {
            _Float16* nb = &hl[(kt + 1) & 1][0];
            GLDS(hn0,      nb + tid * 8);
            GLDS(hn1,      nb + 2048 + tid * 8);
            GLDS(hn0 + 64, nb + 4096 + tid * 8);
            GLDS(hn1 + 64, nb + 6144 + tid * 8);
            hn0 += 128;
            hn1 += 128;
        }

        const _Float16* hbA = &hl[kt & 1][ml << 6];
        const _Float16* hbB = hbA + 4096;

        // ======== 64-key group A (f01/f23) ========
        {
            half4_t afn0 = __builtin_shufflevector(f01, f01, 0, 1, 2, 3);
            half4_t afn1 = __builtin_shufflevector(f01, f01, 4, 5, 6, 7);
            __builtin_amdgcn_s_setprio(1);
            float4_t stA0 = mfma16(afn0, gfA, z4);
            float4_t stB0 = mfma16(afn0, gfB, z4);
            float4_t stA1 = mfma16(afn1, gfA, z4);
            float4_t stB1 = mfma16(afn1, gfB, z4);
            __builtin_amdgcn_s_setprio(0);
            PAIR(stA0, stA1, stB0, stB1, hbA, gxa)

            half4_t afn2 = __builtin_shufflevector(f23, f23, 0, 1, 2, 3);
            half4_t afn3 = __builtin_shufflevector(f23, f23, 4, 5, 6, 7);
            __builtin_amdgcn_s_setprio(1);
            float4_t stA2 = mfma16(afn2, gfA, z4);
            float4_t stB2 = mfma16(afn2, gfB, z4);
            float4_t stA3 = mfma16(afn3, gfA, z4);
            float4_t stB3 = mfma16(afn3, gfB, z4);
            __builtin_amdgcn_s_setprio(0);
            // prefetch next iter's group-A f record
            if (kt + 1 < NT) {
                f01 = *(const half8_t*)(fptr + 2048);
                f23 = *(const half8_t*)(fptr + 2056);
            }
            PAIR(stA2, stA3, stB2, stB3, hbA, gxb)
        }

        // ======== 64-key group B (f45/f67) ========
        {
            half4_t afn0 = __builtin_shufflevector(f45, f45, 0, 1, 2, 3);
            half4_t afn1 = __builtin_shufflevector(f45, f45, 4, 5, 6, 7);
            __builtin_amdgcn_s_setprio(1);
            float4_t stA0 = mfma16(afn0, gfA, z4);
            float4_t stB0 = mfma16(afn0, gfB, z4);
            float4_t stA1 = mfma16(afn1, gfA, z4);
            float4_t stB1 = mfma16(afn1, gfB, z4);
            __builtin_amdgcn_s_setprio(0);
            PAIR(stA0, stA1, stB0, stB1, hbB, gxa)

            half4_t afn2 = __builtin_shufflevector(f67, f67, 0, 1, 2, 3);
            half4_t afn3 = __builtin_shufflevector(f67, f67, 4, 5, 6, 7);
            __builtin_amdgcn_s_setprio(1);
            float4_t stA2 = mfma16(afn2, gfA, z4);
            float4_t stB2 = mfma16(afn2, gfB, z4);
            float4_t stA3 = mfma16(afn3, gfA, z4);
            float4_t stB3 = mfma16(afn3, gfB, z4);
            __builtin_amdgcn_s_setprio(0);
            // prefetch next iter's group-B f record
            if (kt + 1 < NT) {
                f45 = *(const half8_t*)(fptr + 3072);
                f67 = *(const half8_t*)(fptr + 3080);
                fptr += 2048;
            }
            PAIR(stA2, stA3, stB2, stB3, hbB, gxb)
        }

        if (kt + 1 < NT) {
            WAITVM4_BAR();   // retires the 4 tile DMAs; f loads stay in flight
        }
    }

    // ---- store UNNORMALIZED partials + l (from ones-MFMA accumulator) ----
    __half* pa = Pacc + (((size_t)(split * 8 + b) * 64) << 12);
#pragma unroll
    for (int cg = 0; cg < 4; cg++)
#pragma unroll
        for (int r = 0; r < 4; r++) {
            int ch = cg * 16 + q * 4 + r;
            pa[((size_t)ch << 12) + colA] = __float2half(accA[cg][r]);
            pa[((size_t)ch << 12) + colB] = __float2half(accB[cg][r]);
        }
    if (q == 0) {
        Lsum[((size_t)(split * 8 + b) << 12) + colA] = accLA[0];
        Lsum[((size_t)(split * 8 + b) << 12) + colB] = accLB[0];
    }
}

// ---------------- merge ------------------------------------------------------
// grid (64 col-tiles, 8 b, 4 ch-groups of 16), block 256 = 16 ch x 16 col-quads.
template<int S>
__global__ __launch_bounds__(256) void merge_kernel(
    const __half* __restrict__ Pacc, const float* __restrict__ Lsum,
    const float* __restrict__ x, const float* __restrict__ gammap,
    float* __restrict__ out)
{
    __shared__ float invL[64];
    const int tid  = threadIdx.x;
    const int c4   = tid & 15;
    const int chh  = tid >> 4;
    const int b    = blockIdx.y;
    const int col0 = blockIdx.x * 64;
    const int ch   = blockIdx.z * 16 + chh;

    if (tid < 64) {
        float L = 0.f;
#pragma unroll
        for (int s = 0; s < S; s++)
            L += Lsum[((size_t)(s * 8 + b) << 12) + col0 + tid];
        invL[tid] = gammap[0] / L;
    }
    __syncthreads();

    const int cc = c4 * 4;
    const size_t base = (((size_t)b * 64 + ch) << 12) + col0 + cc;
    float4 xv = *(const float4*)(x + base);
    float o0 = 0.f, o1 = 0.f, o2 = 0.f, o3 = 0.f;
#pragma unroll
    for (int s = 0; s < S; s++) {
        half4_t pv = *(const half4_t*)(Pacc +
            (((size_t)(s * 8 + b) * 64 + ch) << 12) + col0 + cc);
        o0 += (float)pv[0];
        o1 += (float)pv[1];
        o2 += (float)pv[2];
        o3 += (float)pv[3];
    }
    float4 ov;
    ov.x = o0 * invL[cc]     + xv.x;
    ov.y = o1 * invL[cc + 1] + xv.y;
    ov.z = o2 * invL[cc + 2] + xv.z;
    ov.w = o3 * invL[cc + 3] + xv.w;
    *(float4*)(out + base) = ov;
}

extern "C" void kernel_launch(void* const* d_in, const int* in_sizes, int n_in,
                              void* d_out, int out_size, void* d_ws, size_t ws_size,
                              hipStream_t stream) {
    const float* x     = (const float*)d_in[0];
    const float* Wq    = (const float*)d_in[1];
    const float* bq    = (const float*)d_in[2];
    const float* Wk    = (const float*)d_in[3];
    const float* bk    = (const float*)d_in[4];
    const float* Wv    = (const float*)d_in[5];
    const float* bv    = (const float*)d_in[6];
    const float* gamma = (const float*)d_in[7];
    float* out = (float*)d_out;

    const size_t fr_bytes  = (size_t)8 * 65536 * 2;             // 1 MB (fTR, 4 q-slots)
    const size_t g_bytes   = (size_t)8 * NTOK * 16 * 2;         // 1 MB
    const size_t hM_bytes  = (size_t)8 * 64 * NTOK * 2;         // 4 MB
    const size_t pa_split  = (size_t)8 * 64 * NTOK * 2;         // 4 MB per split
    const size_t l_split   = (size_t)8 * NTOK * sizeof(float);  // 128 KB per split
    const size_t base_need = fr_bytes + g_bytes + hM_bytes;

    int S = 1;
    if (ws_size >= base_need + 4 * (pa_split + l_split)) S = 4;
    else if (ws_size >= base_need + 2 * (pa_split + l_split)) S = 2;

    char* p = (char*)d_ws;
    __half* fTR  = (__half*)p;  p += fr_bytes;
    __half* gT16 = (__half*)p;  p += g_bytes;
    __half* hM   = (__half*)p;  p += hM_bytes;
    __half* Pacc = (__half*)p;  p += (size_t)S * pa_split;
    float*  Lsum = (float*)p;

    proj_kernel<<<dim3(128, 8), 320, 0, stream>>>(x, Wq, bq, Wk, bk, Wv, bv,
                                                  fTR, gT16, hM);
    if (S == 4) {
        attn_kernel<8><<<dim3(32, 8, 4), 256, 0, stream>>>(fTR, gT16, hM, Pacc, Lsum);
        merge_kernel<4><<<dim3(64, 8, 4), 256, 0, stream>>>(Pacc, Lsum, x, gamma, out);
    } else if (S == 2) {
        attn_kernel<16><<<dim3(32, 8, 2), 256, 0, stream>>>(fTR, gT16, hM, Pacc, Lsum);
        merge_kernel<2><<<dim3(64, 8, 4), 256, 0, stream>>>(Pacc, Lsum, x, gamma, out);
    } else {
        attn_kernel<32><<<dim3(32, 8, 1), 256, 0, stream>>>(fTR, gT16, hM, Pacc, Lsum);
        merge_kernel<1><<<dim3(64, 8, 4), 256, 0, stream>>>(Pacc, Lsum, x, gamma, out);
    }
}

// Round 8
// 114.509 us; speedup vs baseline: 3.7675x; 1.0174x over previous
//
#include <hip/hip_runtime.h>
#include <hip/hip_fp16.h>

// SelfAttention: B=8, C=64, N=4096, d_head=8.
// o[b,c,m] = gamma * sum_n h[b,c,n] * softmax_n(f[:,n].g[:,m]) + x[b,c,m]
// R21 (= R20 with macro fix): (1) attn iter body software-pipelined: ah LDS
// reads issued one PAIR ahead (>=250cyc of work to hide ~120cyc ds_read
// latency), QK blocks interleaved between PAIR consumers so MFMA/VALU phases
// of the 4 lockstep waves mix. (2) proj hM stores coalesced via LDS re-stage
// of xh, 16B/lane. BK=128, vmcnt(4) counted wait, XOR swizzle.
// PAIRC params renamed H0..H3 (R20 bug: N##A0 pasted with the A0 PARAMETER).

typedef _Float16 half8_t __attribute__((ext_vector_type(8)));
typedef _Float16 half4_t __attribute__((ext_vector_type(4)));
typedef _Float16 half2_t __attribute__((ext_vector_type(2)));
typedef __fp16  fp16x2  __attribute__((ext_vector_type(2)));
typedef float float4_t __attribute__((ext_vector_type(4)));
typedef unsigned int uintx4 __attribute__((ext_vector_type(4)));

#define NTOK 4096
#define PRH 72   // proj LDS row stride in halves
#define LOG2E 1.44269504088896340736f

#if __has_builtin(__builtin_amdgcn_exp2f)
__device__ __forceinline__ float fexp2(float x) { return __builtin_amdgcn_exp2f(x); }
#else
__device__ __forceinline__ float fexp2(float x) { return exp2f(x); }
#endif

__device__ __forceinline__ half2_t pkcvt(float a, float b) {
    fp16x2 v = __builtin_amdgcn_cvt_pkrtz(a, b);
    return __builtin_bit_cast(half2_t, v);
}

__device__ __forceinline__ float4_t mfma16(half4_t a, half4_t b, float4_t c) {
    return __builtin_amdgcn_mfma_f32_16x16x16f16(a, b, c, 0, 0, 0);
}
__device__ __forceinline__ float4_t mfma32(half8_t a, half8_t b, float4_t c) {
    return __builtin_amdgcn_mfma_f32_16x16x32_f16(a, b, c, 0, 0, 0);
}

#define GLDS(G, L) __builtin_amdgcn_global_load_lds(                            \
    (const __attribute__((address_space(1))) unsigned int*)(G),                 \
    (__attribute__((address_space(3))) unsigned int*)(L), 16, 0, 0)

// counted wait + raw barrier: the 4 tile-DMAs (issued first this iter) are
// retired; the 4 f-record loads (issued after) may stay in flight
#define WAITVM4_BAR() do {                                                      \
    __builtin_amdgcn_sched_barrier(0);                                          \
    asm volatile("s_waitcnt vmcnt(4)" ::: "memory");                            \
    __builtin_amdgcn_sched_barrier(0);                                          \
    __builtin_amdgcn_s_barrier();                                               \
} while (0)

// ---------------- projection (MFMA) ------------------------------------------
// grid (128 token-tiles of 32, 8 b), block 320 = 5 waves = 5 out-row-groups.
// wave0 rows = Wq(8)+Wk(8); waves1-4 = Wv rows. x staged transposed to LDS
// fp16 with XOR channel swizzle. fTR records: [b][kt64*16+ml][q][t4][4] halves;
// q>=2 slots are the K-pad constants. hM stored PAIRED:
// hM[b][ch][kt64][pos] with pos = (t4>>1)*32 + (ml>>2)*8 + (t4&1)*4 + (ml&3)
// (key = kt64*64 + t4*16 + ml). This block's hM output = contiguous 64B chunk
// (blk&1) per ch row -> staged in LDS (reusing xh) and stored 16B/lane.
__global__ __launch_bounds__(320) void proj_kernel(
    const float* __restrict__ x,
    const float* __restrict__ Wq, const float* __restrict__ bq,
    const float* __restrict__ Wk, const float* __restrict__ bk,
    const float* __restrict__ Wv, const float* __restrict__ bv,
    __half* __restrict__ fTR, __half* __restrict__ gT16, __half* __restrict__ hM)
{
    __shared__ __align__(16) _Float16 xh[32 * PRH];   // 4.6 KB; reused as hstage[64][36]
    const int t      = threadIdx.x;
    const int blk    = blockIdx.x;
    const int b      = blockIdx.y;
    const int n0     = blk * 32;
    const int kt64   = blk >> 1;
    const int t4base = (blk & 1) * 2;

    // stage x[b][c][n0..+31] -> xh[tok][c ^ swz] fp16
    if (t < 256) {
#pragma unroll
        for (int i = 0; i < 2; i++) {
            const int idx = t + i * 256;
            const int c = idx >> 3, f4 = idx & 7;          // tokens f4*4..+3
            float4 v = *(const float4*)(x + (((size_t)(b * 64 + c)) << 12) + n0 + f4 * 4);
            const int cs = c ^ ((f4 & 3) << 4);
            xh[(f4 * 4 + 0) * PRH + cs] = (_Float16)v.x;
            xh[(f4 * 4 + 1) * PRH + cs] = (_Float16)v.y;
            xh[(f4 * 4 + 2) * PRH + cs] = (_Float16)v.z;
            xh[(f4 * 4 + 3) * PRH + cs] = (_Float16)v.w;
        }
    }

    const int w    = t >> 6;
    const int lane = t & 63;
    const int q    = lane >> 4;
    const int ml   = lane & 15;

    // A-frags: W row, k = ks*16 + q*4 + j
    const float* wrow;
    if (w == 0) wrow = (ml < 8) ? (Wq + ml * 64) : (Wk + (ml - 8) * 64);
    else        wrow = Wv + ((w - 1) * 16 + ml) * 64;
    half4_t afr[4];
#pragma unroll
    for (int ks = 0; ks < 4; ks++) {
        float4 wv4 = *(const float4*)(wrow + ks * 16 + q * 4);
        afr[ks] = (half4_t){(_Float16)wv4.x, (_Float16)wv4.y,
                            (_Float16)wv4.z, (_Float16)wv4.w};
    }
    float4 bias4;
    if (w == 0) bias4 = (q < 2) ? *(const float4*)(bq + q * 4)
                                : *(const float4*)(bk + (q - 2) * 4);
    else        bias4 = *(const float4*)(bv + (w - 1) * 16 + q * 4);

    __syncthreads();

    float4_t acc2[2];
#pragma unroll
    for (int cg = 0; cg < 2; cg++) {
        const int tok  = cg * 16 + ml;                  // local token
        const int swz  = (tok >> 2) & 3;
        float4_t acc = (float4_t){0.f, 0.f, 0.f, 0.f};
#pragma unroll
        for (int ks = 0; ks < 4; ks++) {
            half4_t bfr = *(const half4_t*)(&xh[tok * PRH + ((ks ^ swz) * 16 + q * 4)]);
            acc = __builtin_amdgcn_mfma_f32_16x16x16f16(afr[ks], bfr, acc, 0, 0, 0);
        }
        acc[0] += bias4.x; acc[1] += bias4.y; acc[2] += bias4.z; acc[3] += bias4.w;
        acc2[cg] = acc;
        const int gtok = n0 + tok;
        const int t4   = t4base + cg;

        if (w == 0) {
            __half* rec = fTR + ((size_t)b << 16) + (size_t)(kt64 * 16 + ml) * 64;
            if (q < 2) {
                half4_t fv = {(_Float16)(acc[0] * LOG2E), (_Float16)(acc[1] * LOG2E),
                              (_Float16)(acc[2] * LOG2E), (_Float16)(acc[3] * LOG2E)};
                *(half4_t*)(rec + q * 16 + t4 * 4) = fv;
            } else {
                // constant K-pad slots: q2 = {1,0,0,0}, q3 = zeros
                half4_t cv = (half4_t){};
                if (q == 2) cv[0] = (_Float16)1.0f;
                *(half4_t*)(rec + q * 16 + t4 * 4) = cv;
            }
            // g rows live in q>=2 lanes; gn2 via xor16 pairing (q2<->q3)
            float gn2p = acc[0] * acc[0] + acc[1] * acc[1] +
                         acc[2] * acc[2] + acc[3] * acc[3];
            float gn2 = gn2p + __shfl_xor(gn2p, 16, 64);
            if (q >= 2) {
                half4_t gv = {(_Float16)acc[0], (_Float16)acc[1],
                              (_Float16)acc[2], (_Float16)acc[3]};
                __half* gp = gT16 + (size_t)((b << 12) + gtok) * 16;
                *(half4_t*)(gp + (q - 2) * 4) = gv;
                if (q == 2) {
                    const float M = (LOG2E * 4.6f) * __builtin_sqrtf(gn2) + 1.0f;
                    *(half4_t*)(gp + 8) = (half4_t){(_Float16)(-M), 0, 0, 0};
                } else {
                    *(half4_t*)(gp + 12) = (half4_t){};
                }
            }
        }
    }

    // ---- hM epilogue: stage -> coalesced 16B/lane stores ----
    __syncthreads();   // all xh (MFMA B-frag) reads done; safe to overwrite
    if (w > 0) {
        const int ch = (w - 1) * 16 + q * 4;
#pragma unroll
        for (int cg = 0; cg < 2; cg++) {
            const int loc = ((ml >> 2) << 3) + (cg << 2) + (ml & 3);
#pragma unroll
            for (int r = 0; r < 4; r++)
                xh[(ch + r) * 36 + loc] = (_Float16)acc2[cg][r];
        }
    }
    __syncthreads();
    if (t < 256) {
        const int ch   = t >> 2;
        const int part = t & 3;
        half8_t v = *(const half8_t*)(&xh[ch * 36 + part * 8]);
        __half* dst = hM + ((size_t)(b * 64 + ch) << 12) + (size_t)kt64 * 64
                         + (blk & 1) * 32 + part * 8;
        *(half8_t*)dst = v;
    }
}

// ---------------- fused flash attention (key-split, shifted softmax) ---------
// grid (32 colblocks of 128, 8 b, S), block 256 = 4 waves x 32 cols (2 tiles).
// BK=128 keys/iter; per iter: 16 QK mfma16 + 8 ones-l mfma32 + 32 PV mfma32,
// one barrier, 4 GLDS DMA, 4 f b128 loads, vmcnt(4) counted wait.
// ah LDS reads pipelined one PAIR ahead; QK interleaved between PAIRs.

#define LDAH(V0, V1, V2, V3, HP)                                                \
    half8_t V0 = *(const half8_t*)(HP);                                         \
    half8_t V1 = *(const half8_t*)((HP) + 1024);                                \
    half8_t V2 = *(const half8_t*)((HP) + 2048);                                \
    half8_t V3 = *(const half8_t*)((HP) + 3072);

#define QK(F, N)                                                                \
    float4_t N##A0, N##B0, N##A1, N##B1;                                        \
    {                                                                           \
        half4_t a0 = __builtin_shufflevector(F, F, 0, 1, 2, 3);                 \
        half4_t a1 = __builtin_shufflevector(F, F, 4, 5, 6, 7);                 \
        __builtin_amdgcn_s_setprio(1);                                          \
        N##A0 = mfma16(a0, gfA, z4);                                            \
        N##B0 = mfma16(a0, gfB, z4);                                            \
        N##A1 = mfma16(a1, gfA, z4);                                            \
        N##B1 = mfma16(a1, gfB, z4);                                            \
        __builtin_amdgcn_s_setprio(0);                                          \
    }

// NOTE: h-frag params named H0..H3 so N##A0 etc. paste with LITERAL tokens
#define PAIRC(N, H0, H1, H2, H3)                                                \
    {                                                                           \
        float eA0 = fexp2(N##A0[0]), eA1 = fexp2(N##A0[1]),                     \
              eA2 = fexp2(N##A0[2]), eA3 = fexp2(N##A0[3]);                     \
        float oA0 = fexp2(N##A1[0]), oA1 = fexp2(N##A1[1]),                     \
              oA2 = fexp2(N##A1[2]), oA3 = fexp2(N##A1[3]);                     \
        float eB0 = fexp2(N##B0[0]), eB1 = fexp2(N##B0[1]),                     \
              eB2 = fexp2(N##B0[2]), eB3 = fexp2(N##B0[3]);                     \
        float oB0 = fexp2(N##B1[0]), oB1 = fexp2(N##B1[1]),                     \
              oB2 = fexp2(N##B1[2]), oB3 = fexp2(N##B1[3]);                     \
        uintx4 puA = {__builtin_bit_cast(unsigned int, pkcvt(eA0, eA1)),        \
                      __builtin_bit_cast(unsigned int, pkcvt(eA2, eA3)),        \
                      __builtin_bit_cast(unsigned int, pkcvt(oA0, oA1)),        \
                      __builtin_bit_cast(unsigned int, pkcvt(oA2, oA3))};       \
        uintx4 puB = {__builtin_bit_cast(unsigned int, pkcvt(eB0, eB1)),        \
                      __builtin_bit_cast(unsigned int, pkcvt(eB2, eB3)),        \
                      __builtin_bit_cast(unsigned int, pkcvt(oB0, oB1)),        \
                      __builtin_bit_cast(unsigned int, pkcvt(oB2, oB3))};       \
        half8_t pA8 = __builtin_bit_cast(half8_t, puA);                         \
        half8_t pB8 = __builtin_bit_cast(half8_t, puB);                         \
        __builtin_amdgcn_s_setprio(1);                                          \
        accLA = mfma32(ones8, pA8, accLA);                                      \
        accLB = mfma32(ones8, pB8, accLB);                                      \
        accA[0] = mfma32(H0, pA8, accA[0]); accB[0] = mfma32(H0, pB8, accB[0]); \
        accA[1] = mfma32(H1, pA8, accA[1]); accB[1] = mfma32(H1, pB8, accB[1]); \
        accA[2] = mfma32(H2, pA8, accA[2]); accB[2] = mfma32(H2, pB8, accB[2]); \
        accA[3] = mfma32(H3, pA8, accA[3]); accB[3] = mfma32(H3, pB8, accB[3]); \
        __builtin_amdgcn_s_setprio(0);                                          \
    }

template<int NT>
__global__ __launch_bounds__(256) void attn_kernel(
    const __half* __restrict__ fTR, const __half* __restrict__ gT16,
    const __half* __restrict__ hM,
    __half* __restrict__ Pacc, float* __restrict__ Lsum)
{
    __shared__ __align__(16) _Float16 hl[2][8192];  // 2 x 16 KB, [group][ch][64]
    const int tid   = threadIdx.x;
    const int w     = tid >> 6;
    const int lane  = tid & 63;
    const int q     = lane >> 4;
    const int ml    = lane & 15;
    const int m7    = ml & 7;
    const int b     = blockIdx.y;
    const int split = blockIdx.z;
    const int colA  = blockIdx.x * 128 + w * 16 + ml;
    const int colB  = colA + 64;

    half4_t gfA = *(const half4_t*)(gT16 + ((size_t)((b << 12) + colA)) * 16 + q * 4);
    half4_t gfB = *(const half4_t*)(gT16 + ((size_t)((b << 12) + colB)) * 16 + q * 4);

    float4_t accA[4], accB[4];
#pragma unroll
    for (int cg = 0; cg < 4; cg++) {
        accA[cg] = (float4_t){0.f, 0.f, 0.f, 0.f};
        accB[cg] = (float4_t){0.f, 0.f, 0.f, 0.f};
    }
    float4_t accLA = (float4_t){0.f, 0.f, 0.f, 0.f};
    float4_t accLB = (float4_t){0.f, 0.f, 0.f, 0.f};
    const half8_t ones8 = {(_Float16)1.0f, (_Float16)1.0f, (_Float16)1.0f,
                           (_Float16)1.0f, (_Float16)1.0f, (_Float16)1.0f,
                           (_Float16)1.0f, (_Float16)1.0f};
    const float4_t z4 = (float4_t){0.f, 0.f, 0.f, 0.f};

    const int k64 = split * NT * 2;        // first 64-key group index

    // DMA staging: lane-linear LDS dest (tid*16 B), XOR-swizzled global source.
    const int ch0  = tid >> 3;             // 0..31 (part0); part1 adds 32
    const int gsw  = (tid & 7) ^ (ch0 & 7);
    const __half* hs0 = hM + ((size_t)(b * 64 + ch0) << 12) + (size_t)k64 * 64 + gsw * 8;
    const __half* hs1 = hs0 + ((size_t)32 << 12);
    const __half* fptr = fTR + ((size_t)b << 16) + (size_t)(k64 * 16 + ml) * 64 + q * 16;

    // read-side swizzled group offsets (halves)
    const int gxa = ((q ^ m7) << 3);
    const int gxb = (((4 + q) ^ m7) << 3);

    // ---- prologue: DMA 128-key tile 0 + both f records; full drain once ----
    GLDS(hs0,      &hl[0][tid * 8]);
    GLDS(hs1,      &hl[0][2048 + tid * 8]);
    GLDS(hs0 + 64, &hl[0][4096 + tid * 8]);
    GLDS(hs1 + 64, &hl[0][6144 + tid * 8]);
    half8_t f01 = *(const half8_t*)fptr;
    half8_t f23 = *(const half8_t*)(fptr + 8);
    half8_t f45 = *(const half8_t*)(fptr + 1024);
    half8_t f67 = *(const half8_t*)(fptr + 1032);
    __syncthreads();

    const __half* hn0 = hs0 + 128;
    const __half* hn1 = hs1 + 128;

#pragma unroll 1
    for (int kt = 0; kt < NT; kt++) {
        const _Float16* hbA = &hl[kt & 1][ml << 6];
        const _Float16* hbB = hbA + 4096;

        // ---- pipelined body: LDAH one PAIR ahead; QK interleaved ----
        LDAH(a00, a01, a02, a03, hbA + gxa)
        QK(f01, s)

        // issue 4 GLDS for tile kt+1 (vmcnt order: [G x4][f x4])
        if (kt + 1 < NT) {
            _Float16* nb = &hl[(kt + 1) & 1][0];
            GLDS(hn0,      nb + tid * 8);
            GLDS(hn1,      nb + 2048 + tid * 8);
            GLDS(hn0 + 64, nb + 4096 + tid * 8);
            GLDS(hn1 + 64, nb + 6144 + tid * 8);
            hn0 += 128;
            hn1 += 128;
        }

        LDAH(a10, a11, a12, a13, hbA + gxb)
        QK(f23, t)

        PAIRC(s, a00, a01, a02, a03)

        LDAH(a20, a21, a22, a23, hbB + gxa)

        PAIRC(t, a10, a11, a12, a13)

        QK(f45, u)
        LDAH(a30, a31, a32, a33, hbB + gxb)

        PAIRC(u, a20, a21, a22, a23)

        QK(f67, v)
        // prefetch next iter's f records (after all f consumed)
        if (kt + 1 < NT) {
            f01 = *(const half8_t*)(fptr + 2048);
            f23 = *(const half8_t*)(fptr + 2056);
            f45 = *(const half8_t*)(fptr + 3072);
            f67 = *(const half8_t*)(fptr + 3080);
            fptr += 2048;
        }

        PAIRC(v, a30, a31, a32, a33)

        if (kt + 1 < NT) {
            WAITVM4_BAR();   // retires the 4 tile DMAs; f loads stay in flight
        }
    }

    // ---- store UNNORMALIZED partials + l (from ones-MFMA accumulator) ----
    __half* pa = Pacc + (((size_t)(split * 8 + b) * 64) << 12);
#pragma unroll
    for (int cg = 0; cg < 4; cg++)
#pragma unroll
        for (int r = 0; r < 4; r++) {
            int ch = cg * 16 + q * 4 + r;
            pa[((size_t)ch << 12) + colA] = __float2half(accA[cg][r]);
            pa[((size_t)ch << 12) + colB] = __float2half(accB[cg][r]);
        }
    if (q == 0) {
        Lsum[((size_t)(split * 8 + b) << 12) + colA] = accLA[0];
        Lsum[((size_t)(split * 8 + b) << 12) + colB] = accLB[0];
    }
}

// ---------------- merge ------------------------------------------------------
// grid (64 col-tiles, 8 b, 4 ch-groups of 16), block 256 = 16 ch x 16 col-quads.
template<int S>
__global__ __launch_bounds__(256) void merge_kernel(
    const __half* __restrict__ Pacc, const float* __restrict__ Lsum,
    const float* __restrict__ x, const float* __restrict__ gammap,
    float* __restrict__ out)
{
    __shared__ float invL[64];
    const int tid  = threadIdx.x;
    const int c4   = tid & 15;
    const int chh  = tid >> 4;
    const int b    = blockIdx.y;
    const int col0 = blockIdx.x * 64;
    const int ch   = blockIdx.z * 16 + chh;

    if (tid < 64) {
        float L = 0.f;
#pragma unroll
        for (int s = 0; s < S; s++)
            L += Lsum[((size_t)(s * 8 + b) << 12) + col0 + tid];
        invL[tid] = gammap[0] / L;
    }
    __syncthreads();

    const int cc = c4 * 4;
    const size_t base = (((size_t)b * 64 + ch) << 12) + col0 + cc;
    float4 xv = *(const float4*)(x + base);
    float o0 = 0.f, o1 = 0.f, o2 = 0.f, o3 = 0.f;
#pragma unroll
    for (int s = 0; s < S; s++) {
        half4_t pv = *(const half4_t*)(Pacc +
            (((size_t)(s * 8 + b) * 64 + ch) << 12) + col0 + cc);
        o0 += (float)pv[0];
        o1 += (float)pv[1];
        o2 += (float)pv[2];
        o3 += (float)pv[3];
    }
    float4 ov;
    ov.x = o0 * invL[cc]     + xv.x;
    ov.y = o1 * invL[cc + 1] + xv.y;
    ov.z = o2 * invL[cc + 2] + xv.z;
    ov.w = o3 * invL[cc + 3] + xv.w;
    *(float4*)(out + base) = ov;
}

extern "C" void kernel_launch(void* const* d_in, const int* in_sizes, int n_in,
                              void* d_out, int out_size, void* d_ws, size_t ws_size,
                              hipStream_t stream) {
    const float* x     = (const float*)d_in[0];
    const float* Wq    = (const float*)d_in[1];
    const float* bq    = (const float*)d_in[2];
    const float* Wk    = (const float*)d_in[3];
    const float* bk    = (const float*)d_in[4];
    const float* Wv    = (const float*)d_in[5];
    const float* bv    = (const float*)d_in[6];
    const float* gamma = (const float*)d_in[7];
    float* out = (float*)d_out;

    const size_t fr_bytes  = (size_t)8 * 65536 * 2;             // 1 MB (fTR, 4 q-slots)
    const size_t g_bytes   = (size_t)8 * NTOK * 16 * 2;         // 1 MB
    const size_t hM_bytes  = (size_t)8 * 64 * NTOK * 2;         // 4 MB
    const size_t pa_split  = (size_t)8 * 64 * NTOK * 2;         // 4 MB per split
    const size_t l_split   = (size_t)8 * NTOK * sizeof(float);  // 128 KB per split
    const size_t base_need = fr_bytes + g_bytes + hM_bytes;

    int S = 1;
    if (ws_size >= base_need + 4 * (pa_split + l_split)) S = 4;
    else if (ws_size >= base_need + 2 * (pa_split + l_split)) S = 2;

    char* p = (char*)d_ws;
    __half* fTR  = (__half*)p;  p += fr_bytes;
    __half* gT16 = (__half*)p;  p += g_bytes;
    __half* hM   = (__half*)p;  p += hM_bytes;
    __half* Pacc = (__half*)p;  p += (size_t)S * pa_split;
    float*  Lsum = (float*)p;

    proj_kernel<<<dim3(128, 8), 320, 0, stream>>>(x, Wq, bq, Wk, bk, Wv, bv,
                                                  fTR, gT16, hM);
    if (S == 4) {
        attn_kernel<8><<<dim3(32, 8, 4), 256, 0, stream>>>(fTR, gT16, hM, Pacc, Lsum);
        merge_kernel<4><<<dim3(64, 8, 4), 256, 0, stream>>>(Pacc, Lsum, x, gamma, out);
    } else if (S == 2) {
        attn_kernel<16><<<dim3(32, 8, 2), 256, 0, stream>>>(fTR, gT16, hM, Pacc, Lsum);
        merge_kernel<2><<<dim3(64, 8, 4), 256, 0, stream>>>(Pacc, Lsum, x, gamma, out);
    } else {
        attn_kernel<32><<<dim3(32, 8, 1), 256, 0, stream>>>(fTR, gT16, hM, Pacc, Lsum);
        merge_kernel<1><<<dim3(64, 8, 4), 256, 0, stream>>>(Pacc, Lsum, x, gamma, out);
    }
}